// Round 1
// baseline (263.007 us; speedup 1.0000x reference)
//
#include <hip/hip_runtime.h>

// SSIM over (16,3,512,512) f32: five 11x11 depthwise Gaussian convs (zero pad),
// pointwise SSIM, global mean. Fused single pass with separable conv in LDS.

#define KSZ   11
#define PAD   5
#define TILE  32
#define HALO  (TILE + KSZ - 1)   // 42
#define NTHREADS 256

__global__ __launch_bounds__(NTHREADS) void ssim_zero_acc(double* acc) {
    if (threadIdx.x == 0 && blockIdx.x == 0) acc[0] = 0.0;
}

__global__ __launch_bounds__(NTHREADS)
void ssim_main(const float* __restrict__ img1,
               const float* __restrict__ img2,
               const float* __restrict__ window,
               double* __restrict__ acc,
               int H, int W)
{
    __shared__ float k1d[KSZ];
    __shared__ float sx1[HALO][HALO];
    __shared__ float sx2[HALO][HALO];
    __shared__ float h0[HALO][TILE];   // conv_h(x1)
    __shared__ float h1[HALO][TILE];   // conv_h(x2)
    __shared__ float h2[HALO][TILE];   // conv_h(x1*x1)
    __shared__ float h3[HALO][TILE];   // conv_h(x2*x2)
    __shared__ float h4[HALO][TILE];   // conv_h(x1*x2)
    __shared__ float red[NTHREADS / 64];

    const int tid = threadIdx.x;
    const int bx  = blockIdx.x * TILE;
    const int by  = blockIdx.y * TILE;
    const size_t planeOff = (size_t)blockIdx.z * H * W;
    const float* p1 = img1 + planeOff;
    const float* p2 = img2 + planeOff;

    // 1D kernel = row sums of the 2D window (window = outer(k,k), sum(k)=1).
    if (tid < KSZ) {
        float s = 0.f;
        #pragma unroll
        for (int j = 0; j < KSZ; ++j) s += window[tid * KSZ + j];
        k1d[tid] = s;
    }

    // Stage halo tiles; zero outside the image (matches zero padding).
    for (int idx = tid; idx < HALO * HALO; idx += NTHREADS) {
        const int r = idx / HALO, c = idx % HALO;
        const int gr = by + r - PAD, gc = bx + c - PAD;
        float v1 = 0.f, v2 = 0.f;
        if (gr >= 0 && gr < H && gc >= 0 && gc < W) {
            const size_t g = (size_t)gr * W + gc;
            v1 = p1[g];
            v2 = p2[g];
        }
        sx1[r][c] = v1;
        sx2[r][c] = v2;
    }
    __syncthreads();

    // Horizontal pass: 42 rows x 32 cols, 5 fields.
    for (int idx = tid; idx < HALO * TILE; idx += NTHREADS) {
        const int r = idx / TILE, c = idx % TILE;
        float a0 = 0.f, a1 = 0.f, a2 = 0.f, a3 = 0.f, a4 = 0.f;
        #pragma unroll
        for (int k = 0; k < KSZ; ++k) {
            const float w  = k1d[k];
            const float x1 = sx1[r][c + k];
            const float x2 = sx2[r][c + k];
            a0 += w * x1;
            a1 += w * x2;
            a2 += w * (x1 * x1);
            a3 += w * (x2 * x2);
            a4 += w * (x1 * x2);
        }
        h0[r][c] = a0; h1[r][c] = a1; h2[r][c] = a2; h3[r][c] = a3; h4[r][c] = a4;
    }
    __syncthreads();

    // Vertical pass + SSIM + per-thread partial sum.
    const float C1 = 1e-4f;   // 0.01^2
    const float C2 = 9e-4f;   // 0.03^2
    float lsum = 0.f;
    for (int idx = tid; idx < TILE * TILE; idx += NTHREADS) {
        const int r = idx / TILE, c = idx % TILE;
        float mu1 = 0.f, mu2 = 0.f, e11 = 0.f, e22 = 0.f, e12 = 0.f;
        #pragma unroll
        for (int k = 0; k < KSZ; ++k) {
            const float w = k1d[k];
            mu1 += w * h0[r + k][c];
            mu2 += w * h1[r + k][c];
            e11 += w * h2[r + k][c];
            e22 += w * h3[r + k][c];
            e12 += w * h4[r + k][c];
        }
        const float mu1_sq = mu1 * mu1;
        const float mu2_sq = mu2 * mu2;
        const float mu1mu2 = mu1 * mu2;
        const float s11 = e11 - mu1_sq;
        const float s22 = e22 - mu2_sq;
        const float s12 = e12 - mu1mu2;
        const float num = (2.f * mu1mu2 + C1) * (2.f * s12 + C2);
        const float den = (mu1_sq + mu2_sq + C1) * (s11 + s22 + C2);
        lsum += num / den;
    }

    // Wave (64-lane) reduction, then cross-wave via LDS, then one atomic/block.
    #pragma unroll
    for (int off = 32; off > 0; off >>= 1)
        lsum += __shfl_down(lsum, off, 64);
    const int wave = tid >> 6;
    const int lane = tid & 63;
    if (lane == 0) red[wave] = lsum;
    __syncthreads();
    if (tid == 0) {
        float bsum = 0.f;
        #pragma unroll
        for (int w = 0; w < NTHREADS / 64; ++w) bsum += red[w];
        atomicAdd(acc, (double)bsum);
    }
}

__global__ __launch_bounds__(64) void ssim_finalize(const double* acc, float* out, double invN) {
    if (threadIdx.x == 0 && blockIdx.x == 0) out[0] = (float)(acc[0] * invN);
}

extern "C" void kernel_launch(void* const* d_in, const int* in_sizes, int n_in,
                              void* d_out, int out_size, void* d_ws, size_t ws_size,
                              hipStream_t stream) {
    const float* img1   = (const float*)d_in[0];
    const float* img2   = (const float*)d_in[1];
    const float* window = (const float*)d_in[2];
    float* out = (float*)d_out;
    double* acc = (double*)d_ws;

    // Shapes fixed by the reference: (16,3,512,512)
    const int N = 16, C = 3, H = 512, W = 512;
    const long long total = (long long)N * C * H * W;

    ssim_zero_acc<<<1, NTHREADS, 0, stream>>>(acc);

    dim3 grid(W / TILE, H / TILE, N * C);
    ssim_main<<<grid, NTHREADS, 0, stream>>>(img1, img2, window, acc, H, W);

    ssim_finalize<<<1, 64, 0, stream>>>(acc, out, 1.0 / (double)total);
}